// Round 13
// baseline (4636.739 us; speedup 1.0000x reference)
//
#include <hip/hip_runtime.h>

// 10x [ y = x @ W_in^T + b_in ; LN ; x = y @ W_out^T + b_out ; LN ]
// Mrows=16384, d_in=1024, d_out=4096. Output f32.
// R13: N-persistent GEMM1 (NP=4): grid 256 = ONE generation; each block
// sweeps 4 N-panels (one 1024-col N-group) sequentially, reusing its
// A-panel (L2/L3) and amortizing the ~30us per-block overhead 4x.
// Panel boundaries are store-isolated: vmcnt(0)+barrier drain, then a
// fresh per-panel prologue (unlike R6's interleaved M-persistence whose
// counted vmcnt collided with epilogue stores). XCD map: 2 XCDs per
// N-group -> per-XCD B set 2MB L2-resident. GEMM2 = R12 (NP=1).

typedef __attribute__((ext_vector_type(4))) float    f32x4;
typedef __attribute__((ext_vector_type(8))) _Float16 f16x8;
typedef __attribute__((ext_vector_type(4))) _Float16 f16x4;
typedef __attribute__((ext_vector_type(4))) uint     u32x4;

#define LN_EPS 1e-5f

__device__ __forceinline__ ushort f2h_bits(float f) {
    union { _Float16 h; ushort u; } c; c.h = (_Float16)f; return c.u;
}

typedef const __attribute__((address_space(1))) void* gas_ptr;
typedef __attribute__((address_space(3))) void* las_ptr;

__device__ __forceinline__ void gload_lds16(const void* g, void* l) {
    __builtin_amdgcn_global_load_lds((gas_ptr)g, (las_ptr)l, 16, 0, 0);
}

__device__ __forceinline__ f16x8 ldf(const _Float16* base, int byteoff) {
    return *reinterpret_cast<const f16x8*>(
        reinterpret_cast<const char*>(base) + byteoff);
}

// ---------------------------------------------------------------------------
__global__ __launch_bounds__(256) void conv_f32_f16(
        const float* __restrict__ in, _Float16* __restrict__ outp, int n4) {
    int i = blockIdx.x * 256 + threadIdx.x;
    if (i >= n4) return;
    float4 f = reinterpret_cast<const float4*>(in)[i];
    f16x4 r;
    r[0] = (_Float16)f.x; r[1] = (_Float16)f.y;
    r[2] = (_Float16)f.z; r[3] = (_Float16)f.w;
    *reinterpret_cast<f16x4*>(&outp[(size_t)i * 4]) = r;
}

// ---------------------------------------------------------------------------
template<int W>
__global__ __launch_bounds__(256)
void rowsum_rows(const _Float16* __restrict__ w, float* __restrict__ outp) {
    const int wid  = threadIdx.x >> 6;
    const int lane = threadIdx.x & 63;
    const size_t row = (size_t)blockIdx.x * 4 + wid;
    const _Float16* p = w + row * W;
    float s = 0.f;
    #pragma unroll
    for (int i = 0; i < W / 512; ++i) {
        f16x8 v = *reinterpret_cast<const f16x8*>(p + i * 512 + lane * 8);
        #pragma unroll
        for (int j = 0; j < 8; ++j) s += (float)v[j];
    }
    #pragma unroll
    for (int off = 32; off > 0; off >>= 1) s += __shfl_xor(s, off);
    if (lane == 0) outp[row] = s;
}

// ---------------------------------------------------------------------------
// C[M,N](f16) = LN-fold of A_raw[M,K](f16) * B[N,K]^T(f16):
//   out = rs*(A.B^T) - (rs*mean)*wsum[n] + bias[n]
// (mean,rs) computed IN-BLOCK from pin (previous kernel's partials).
// Emits partials[row][bn0>>8] = (sum, sumsq) over 256-col panel.
// 256x256 tile, BK=64, 512 thr = 8 waves (2Mx4N), 8-phase pipeline.
// NP: N-panels swept per block (4 = N-persistent GEMM1, 1 = GEMM2).
// ---------------------------------------------------------------------------
template<int M, int N, int K, int NP, bool FIRST>
__global__ __launch_bounds__(512)
void gemm256_ln(const _Float16* __restrict__ A, const _Float16* __restrict__ B,
                const float* __restrict__ bias, const float* __restrict__ wsum,
                const float2* __restrict__ pin, _Float16* __restrict__ C,
                float2* __restrict__ partials) {
    constexpr int NT   = K / 64;
    constexpr int NIT  = NT / 2;
    constexpr int NBX  = N / 256;
    constexpr int NPIN = K / 256;

    __shared__ __attribute__((aligned(16))) _Float16 lds[2][2][2][8192];

    const int tid  = threadIdx.x;
    const int wid  = tid >> 6;
    const int lane = tid & 63;
    const int wr   = wid >> 2;          // 0..1
    const int wc   = wid & 3;           // 0..3

    int bn_base, bm0;
    if constexpr (NP == 4) {
        // N-persistent: XCD pair (x>>1) owns one 1024-col N-group; the two
        // XCDs of a pair split M. grid = 64 M-panels x 4 N-groups = 256.
        const int x = blockIdx.x & 7, j = blockIdx.x >> 3;   // j 0..31
        bn_base = (x >> 1) * 1024;
        bm0     = ((x & 1) * 32 + j) * 256;
    } else {
        // NBX==4 pair-split (GEMM2): XCD x owns N-panel x>>1, M-parity x&1.
        const int x = blockIdx.x & 7, j = blockIdx.x >> 3;
        bn_base = (x >> 1) * 256;
        bm0     = (j * 2 + (x & 1)) * 256;
    }

    const int trow = tid >> 3;                    // 0..63
    const int cg   = (tid & 7) ^ (trow & 7);      // inverse swizzle on source
    const _Float16* Asrc = A + (size_t)(bm0 + trow) * K + cg * 8;

    const int fr  = lane & 15;
    const int fq  = lane >> 4;
    const int s8  = lane & 7;
    const int cb0 = ((fq       ^ s8) << 4);
    const int cb1 = (((4 + fq) ^ s8) << 4);
    const int brb = (wc & 1) * 64;

    const _Float16* Ah[2] = { &lds[0][0][wr][0],      &lds[1][0][wr][0] };
    const _Float16* Bh[2] = { &lds[0][1][wc >> 1][0], &lds[1][1][wc >> 1][0] };

#define STAGE_A(buf, h, kk) do { \
    gload_lds16(Asrc + (size_t)((h)*128     ) * K + (kk), (void*)&lds[buf][0][h][       wid*512]); \
    gload_lds16(Asrc + (size_t)((h)*128 + 64) * K + (kk), (void*)&lds[buf][0][h][4096 + wid*512]); } while(0)
#define STAGE_B(buf, h, kk) do { \
    gload_lds16(Bsrc + (size_t)((h)*128     ) * K + (kk), (void*)&lds[buf][1][h][       wid*512]); \
    gload_lds16(Bsrc + (size_t)((h)*128 + 64) * K + (kk), (void*)&lds[buf][1][h][4096 + wid*512]); } while(0)

#define READ_ALO(b) do { _Pragma("unroll") for (int i = 0; i < 4; ++i) { \
    aLo[i][0] = ldf(Ah[b], (i*16+fr)*128 + cb0); \
    aLo[i][1] = ldf(Ah[b], (i*16+fr)*128 + cb1); } } while(0)
#define READ_AHI(b) do { _Pragma("unroll") for (int i = 0; i < 4; ++i) { \
    aHi[i][0] = ldf(Ah[b], ((i+4)*16+fr)*128 + cb0); \
    aHi[i][1] = ldf(Ah[b], ((i+4)*16+fr)*128 + cb1); } } while(0)
#define READ_BLO(b) do { _Pragma("unroll") for (int j = 0; j < 2; ++j) { \
    bLo[j][0] = ldf(Bh[b], (brb + j*16 + fr)*128 + cb0); \
    bLo[j][1] = ldf(Bh[b], (brb + j*16 + fr)*128 + cb1); } } while(0)
#define READ_BHI(b) do { _Pragma("unroll") for (int j = 0; j < 2; ++j) { \
    bHi[j][0] = ldf(Bh[b], (brb + (j+2)*16 + fr)*128 + cb0); \
    bHi[j][1] = ldf(Bh[b], (brb + (j+2)*16 + fr)*128 + cb1); } } while(0)

#define MFMA_BLK(AF, ioff, BF, joff) do { \
    _Pragma("unroll") for (int i = 0; i < 4; ++i) \
    _Pragma("unroll") for (int j = 0; j < 2; ++j) { \
        acc[i+ioff][j+joff] = __builtin_amdgcn_mfma_f32_16x16x32_f16(AF[i][0], BF[j][0], acc[i+ioff][j+joff], 0, 0, 0); \
        acc[i+ioff][j+joff] = __builtin_amdgcn_mfma_f32_16x16x32_f16(AF[i][1], BF[j][1], acc[i+ioff][j+joff], 0, 0, 0); } } while(0)

#define BARRIER() __builtin_amdgcn_s_barrier()
#define VMCNT4()  asm volatile("s_waitcnt vmcnt(4)" ::: "memory")
#define VMCNT0()  asm volatile("s_waitcnt vmcnt(0)" ::: "memory")

    for (int p = 0; p < NP; ++p) {
        const int bn0 = bn_base + p * 256;
        const _Float16* Bsrc = B + (size_t)(bn0 + trow) * K + cg * 8;

        // panel boundary: drain epilogue stores + stale wrap prefetches
        if (p) { VMCNT0(); BARRIER(); }

        // prologue: tile0 -> buf0 (A+B), tile1 B-halves -> buf1
        STAGE_B(0, 0, 0);  STAGE_B(0, 1, 0);
        STAGE_A(0, 0, 0);  STAGE_A(0, 1, 0);
        STAGE_B(1, 0, 64); STAGE_B(1, 1, 64);
        VMCNT4();
        BARRIER();

        f32x4 acc[8][4] = {};
        f16x8 aLo[4][2], aHi[4][2], bLo[2][2], bHi[2][2];

        for (int it = 0; it < NIT; ++it) {
            const int k1 = it * 128 + 64;
            const int k2 = (it * 128 + 128) & (K - 1);   // wrap staging (R7)
            const int k3 = (it * 128 + 192) & (K - 1);

            // ph0
            READ_ALO(0); READ_BLO(0);
            STAGE_A(1, 0, k1);
            BARRIER();
            __builtin_amdgcn_s_setprio(1); MFMA_BLK(aLo, 0, bLo, 0); __builtin_amdgcn_s_setprio(0);
            BARRIER();
            // ph1
            READ_BHI(0);
            STAGE_A(1, 1, k1);
            BARRIER();
            __builtin_amdgcn_s_setprio(1); MFMA_BLK(aLo, 0, bHi, 2); __builtin_amdgcn_s_setprio(0);
            BARRIER();
            // ph2
            READ_AHI(0);
            STAGE_B(0, 0, k2);
            BARRIER();
            __builtin_amdgcn_s_setprio(1); MFMA_BLK(aHi, 4, bLo, 0); __builtin_amdgcn_s_setprio(0);
            BARRIER();
            // ph3
            STAGE_B(0, 1, k2);
            BARRIER();
            __builtin_amdgcn_s_setprio(1); MFMA_BLK(aHi, 4, bHi, 2); __builtin_amdgcn_s_setprio(0);
            VMCNT4();
            BARRIER();
            // ph4
            READ_ALO(1); READ_BLO(1);
            STAGE_A(0, 0, k2);
            BARRIER();
            __builtin_amdgcn_s_setprio(1); MFMA_BLK(aLo, 0, bLo, 0); __builtin_amdgcn_s_setprio(0);
            BARRIER();
            // ph5
            READ_BHI(1);
            STAGE_A(0, 1, k2);
            BARRIER();
            __builtin_amdgcn_s_setprio(1); MFMA_BLK(aLo, 0, bHi, 2); __builtin_amdgcn_s_setprio(0);
            BARRIER();
            // ph6
            READ_AHI(1);
            STAGE_B(1, 0, k3);
            BARRIER();
            __builtin_amdgcn_s_setprio(1); MFMA_BLK(aHi, 4, bLo, 0); __builtin_amdgcn_s_setprio(0);
            BARRIER();
            // ph7
            STAGE_B(1, 1, k3);
            BARRIER();
            __builtin_amdgcn_s_setprio(1); MFMA_BLK(aHi, 4, bHi, 2); __builtin_amdgcn_s_setprio(0);
            VMCNT4();
            BARRIER();
        }

        // ---- in-block stats: reduce pin -> sst[256] in dead buf0-A (2 KB) --
        float2* sst = (float2*)&lds[0][0][0][0];
        if constexpr (FIRST) {
            if (tid < 256) sst[tid] = make_float2(0.f, 1.f);
        } else {
            const int row  = tid >> 1;
            const int half = tid & 1;
            const float2* pr = pin + (size_t)(bm0 + row) * NPIN + half * (NPIN / 2);
            float s = 0.f, q = 0.f;
            #pragma unroll
            for (int k = 0; k < NPIN / 2; ++k) { s += pr[k].x; q += pr[k].y; }
            s += __shfl_xor(s, 1); q += __shfl_xor(q, 1);
            if (half == 0) {
                const float mean = s * (1.0f / K);
                const float var  = fmaxf(q * (1.0f / K) - mean * mean, 0.f);
                sst[row] = make_float2(mean, rsqrtf(var + LN_EPS));
            }
        }
        __syncthreads();

        float bcol[4], wcol[4];
        #pragma unroll
        for (int j = 0; j < 4; ++j) {
            const int c = bn0 + wc * 64 + j * 16 + fr;
            bcol[j] = bias[c]; wcol[j] = wsum[c];
        }

        // ---- epilogue through buf1-A (safe per vmcnt ledger) ----
        ushort* eps = (ushort*)&lds[1][0][0][0];   // 64 x 256 ushort = 32 KiB
        #pragma unroll
        for (int pass = 0; pass < 4; ++pass) {
            if (wr == (pass >> 1)) {
                #pragma unroll
                for (int i2 = 0; i2 < 4; ++i2) {
                    const int i = (pass & 1) * 4 + i2;
                    #pragma unroll
                    for (int q = 0; q < 4; ++q) {
                        const int rloc = wr * 128 + i * 16 + fq * 4 + q; // m89
                        const int rl   = rloc - pass * 64;               // 0..63
                        const float2 st = sst[rloc];
                        const float rs = st.y, coef = st.y * st.x;
                        const int key = ((rl >> 2) & 3) << 4;
                        #pragma unroll
                        for (int j = 0; j < 4; ++j) {
                            const float v = rs * acc[i][j][q] - coef * wcol[j] + bcol[j];
                            const int c = wc * 64 + j * 16 + fr;
                            eps[rl * 256 + (c ^ key)] = f2h_bits(v);
                        }
                    }
                }
            }
            BARRIER();
            {
                const int rl  = tid >> 3;          // 0..63
                const int a8  = tid & 7;
                const int r   = bm0 + pass * 64 + rl;
                const int key = ((rl >> 2) & 3) << 4;
                float s = 0.f, sq = 0.f;
                ushort* crow = (ushort*)(C + (size_t)r * N + bn0);
                #pragma unroll
                for (int k = 0; k < 4; ++k) {
                    const int ch = 8 * k + a8;     // physical 16B chunk
                    u32x4 d = *reinterpret_cast<const u32x4*>(&eps[rl * 256 + ch * 8]);
                    const f16x8 v = *reinterpret_cast<const f16x8*>(&d);
                    #pragma unroll
                    for (int e = 0; e < 8; ++e) {
                        const float f = (float)v[e];
                        s += f; sq += f * f;
                    }
                    *reinterpret_cast<u32x4*>(&crow[(ch * 8) ^ key]) = d;
                }
                s  += __shfl_xor(s, 1);  sq += __shfl_xor(sq, 1);
                s  += __shfl_xor(s, 2);  sq += __shfl_xor(sq, 2);
                s  += __shfl_xor(s, 4);  sq += __shfl_xor(sq, 4);
                if (a8 == 0)
                    partials[(size_t)r * NBX + (bn0 >> 8)] = make_float2(s, sq);
            }
            BARRIER();
        }
    }
#undef STAGE_A
#undef STAGE_B
#undef READ_ALO
#undef READ_AHI
#undef READ_BLO
#undef READ_BHI
#undef MFMA_BLK
#undef BARRIER
#undef VMCNT4
#undef VMCNT0
}

// ---------------------------------------------------------------------------
// Final: reduce 4 partials/row -> (mean, rstd); out_f32 = (a - mean)*rstd.
// ---------------------------------------------------------------------------
__global__ __launch_bounds__(256)
void ln_final(const _Float16* __restrict__ a, const float2* __restrict__ part,
              float* __restrict__ outp) {
    const int wid  = threadIdx.x >> 6;
    const int lane = threadIdx.x & 63;
    const size_t row = (size_t)blockIdx.x * 4 + wid;

    float s = 0.f, q = 0.f;
    if (lane < 4) { const float2 p = part[row * 4 + lane]; s = p.x; q = p.y; }
    s += __shfl_xor(s, 1); q += __shfl_xor(q, 1);
    s += __shfl_xor(s, 2); q += __shfl_xor(q, 2);
    s = __shfl(s, 0); q = __shfl(q, 0);
    const float mean = s * (1.0f / 1024.f);
    const float var  = fmaxf(q * (1.0f / 1024.f) - mean * mean, 0.f);
    const float rstd = rsqrtf(var + LN_EPS);

    const _Float16* p = a + row * 1024;
    #pragma unroll
    for (int i = 0; i < 2; ++i) {
        f16x8 v = *reinterpret_cast<const f16x8*>(p + i * 512 + lane * 8);
        float* op = outp + row * 1024 + i * 512 + lane * 8;
        float4 o0, o1;
        o0.x = ((float)v[0] - mean) * rstd;
        o0.y = ((float)v[1] - mean) * rstd;
        o0.z = ((float)v[2] - mean) * rstd;
        o0.w = ((float)v[3] - mean) * rstd;
        o1.x = ((float)v[4] - mean) * rstd;
        o1.y = ((float)v[5] - mean) * rstd;
        o1.z = ((float)v[6] - mean) * rstd;
        o1.w = ((float)v[7] - mean) * rstd;
        reinterpret_cast<float4*>(op)[0] = o0;
        reinterpret_cast<float4*>(op)[1] = o1;
    }
}

// ---------------------------------------------------------------------------
extern "C" void kernel_launch(void* const* d_in, const int* in_sizes, int n_in,
                              void* d_out, int out_size, void* d_ws, size_t ws_size,
                              hipStream_t stream) {
    const float* x     = (const float*)d_in[0];
    const float* w_in  = (const float*)d_in[1];
    const float* b_in  = (const float*)d_in[2];
    const float* w_out = (const float*)d_in[3];
    const float* b_out = (const float*)d_in[4];

    constexpr int Mrows = 16384;
    constexpr int Din   = 1024;
    constexpr int Dout  = 4096;

    char* ws = (char*)d_ws;
    _Float16* wib = (_Float16*)ws; ws += (size_t)Dout * Din * 2;      // 8 MB
    _Float16* wob = (_Float16*)ws; ws += (size_t)Din * Dout * 2;      // 8 MB
    _Float16* a2b = (_Float16*)ws; ws += (size_t)Mrows * Din * 2;     // 32 MB
    _Float16* a1b = (_Float16*)ws; ws += (size_t)Mrows * Dout * 2;    // 128 MB
    float* winsum  = (float*)ws;   ws += Dout * 4;                    // 16 KB
    float* woutsum = (float*)ws;   ws += Din * 4;                     // 4 KB
    float2* p1  = (float2*)ws;     ws += (size_t)Mrows * 16 * 8;      // 2 MB
    float2* p2  = (float2*)ws;                                        // 0.5 MB

    const dim3 blk(256);

    conv_f32_f16<<<(Dout * Din / 4) / 256, blk, 0, stream>>>(w_in,  wib, Dout * Din / 4);
    conv_f32_f16<<<(Din * Dout / 4) / 256, blk, 0, stream>>>(w_out, wob, Din * Dout / 4);
    conv_f32_f16<<<(Mrows * Din / 4) / 256, blk, 0, stream>>>(x, a2b, Mrows * Din / 4);
    rowsum_rows<Din> <<<Dout / 4, blk, 0, stream>>>(wib, winsum);
    rowsum_rows<Dout><<<Din / 4,  blk, 0, stream>>>(wob, woutsum);

    for (int it = 0; it < 10; ++it) {
        if (it == 0)
            gemm256_ln<Mrows, Dout, Din, 4, true>
                <<<256, dim3(512), 0, stream>>>(a2b, wib, b_in, winsum, p2, a1b, p1);
        else
            gemm256_ln<Mrows, Dout, Din, 4, false>
                <<<256, dim3(512), 0, stream>>>(a2b, wib, b_in, winsum, p2, a1b, p1);
        gemm256_ln<Mrows, Din, Dout, 1, false>
            <<<256, dim3(512), 0, stream>>>(a1b, wob, b_out, woutsum, p1, a2b, p2);
    }
    ln_final<<<Mrows / 4, blk, 0, stream>>>(a2b, p2, (float*)d_out);
}

// Round 14
// 2758.280 us; speedup vs baseline: 1.6810x; 1.6810x over previous
//
#include <hip/hip_runtime.h>

// 10x [ y = x @ W_in^T + b_in ; LN ; x = y @ W_out^T + b_out ; LN ]
// Mrows=16384, d_in=1024, d_out=4096. Output f32.
// R14 = R11 exact revert (best measured: 2798us). R13's N-persistence
// doubled FETCH (A reuse distance >> L2 capacity-time) and was reverted.
// Config: fp16 MFMA 256^2 8-phase GEMMs, LN folded into epilogue
// (out = rs*(A.B^T) - rs*mean*wsum + bias), stats computed in-block from
// previous kernel's partials (no fence, no atomics), partials emitted in
// the conflict-free LDS-transpose epilogue readback.

typedef __attribute__((ext_vector_type(4))) float    f32x4;
typedef __attribute__((ext_vector_type(8))) _Float16 f16x8;
typedef __attribute__((ext_vector_type(4))) _Float16 f16x4;
typedef __attribute__((ext_vector_type(4))) uint     u32x4;

#define LN_EPS 1e-5f

__device__ __forceinline__ ushort f2h_bits(float f) {
    union { _Float16 h; ushort u; } c; c.h = (_Float16)f; return c.u;
}

typedef const __attribute__((address_space(1))) void* gas_ptr;
typedef __attribute__((address_space(3))) void* las_ptr;

__device__ __forceinline__ void gload_lds16(const void* g, void* l) {
    __builtin_amdgcn_global_load_lds((gas_ptr)g, (las_ptr)l, 16, 0, 0);
}

__device__ __forceinline__ f16x8 ldf(const _Float16* base, int byteoff) {
    return *reinterpret_cast<const f16x8*>(
        reinterpret_cast<const char*>(base) + byteoff);
}

// ---------------------------------------------------------------------------
__global__ __launch_bounds__(256) void conv_f32_f16(
        const float* __restrict__ in, _Float16* __restrict__ outp, int n4) {
    int i = blockIdx.x * 256 + threadIdx.x;
    if (i >= n4) return;
    float4 f = reinterpret_cast<const float4*>(in)[i];
    f16x4 r;
    r[0] = (_Float16)f.x; r[1] = (_Float16)f.y;
    r[2] = (_Float16)f.z; r[3] = (_Float16)f.w;
    *reinterpret_cast<f16x4*>(&outp[(size_t)i * 4]) = r;
}

// ---------------------------------------------------------------------------
template<int W>
__global__ __launch_bounds__(256)
void rowsum_rows(const _Float16* __restrict__ w, float* __restrict__ outp) {
    const int wid  = threadIdx.x >> 6;
    const int lane = threadIdx.x & 63;
    const size_t row = (size_t)blockIdx.x * 4 + wid;
    const _Float16* p = w + row * W;
    float s = 0.f;
    #pragma unroll
    for (int i = 0; i < W / 512; ++i) {
        f16x8 v = *reinterpret_cast<const f16x8*>(p + i * 512 + lane * 8);
        #pragma unroll
        for (int j = 0; j < 8; ++j) s += (float)v[j];
    }
    #pragma unroll
    for (int off = 32; off > 0; off >>= 1) s += __shfl_xor(s, off);
    if (lane == 0) outp[row] = s;
}

// ---------------------------------------------------------------------------
// C[M,N](f16) = LN-fold of A_raw[M,K](f16) * B[N,K]^T(f16):
//   out = rs*(A.B^T) - (rs*mean)*wsum[n] + bias[n]
// (mean,rs) computed IN-BLOCK from pin (previous kernel's partials,
//  NPIN = K/256 entries per row); FIRST: identity stats (raw first layer).
// Emits partials[row][bn0>>8] = (sum, sumsq) over this block's 256 cols.
// 256x256 tile, BK=64, 512 thr = 8 waves (2Mx4N), 8-phase pipeline.
// ---------------------------------------------------------------------------
template<int M, int N, int K, bool FIRST>
__global__ __launch_bounds__(512)
void gemm256_ln(const _Float16* __restrict__ A, const _Float16* __restrict__ B,
                const float* __restrict__ bias, const float* __restrict__ wsum,
                const float2* __restrict__ pin, _Float16* __restrict__ C,
                float2* __restrict__ partials) {
    constexpr int NT   = K / 64;
    constexpr int NIT  = NT / 2;
    constexpr int NBX  = N / 256;
    constexpr int NWG  = (M / 256) * NBX;
    constexpr int NPIN = K / 256;

    __shared__ __attribute__((aligned(16))) _Float16 lds[2][2][2][8192];

    const int tid  = threadIdx.x;
    const int wid  = tid >> 6;
    const int lane = tid & 63;
    const int wr   = wid >> 2;          // 0..1
    const int wc   = wid & 3;           // 0..3

    int bn0, bm0;
    if constexpr (NBX == 16) {
        // N-strip: XCD x owns N-panels {2x,2x+1}, all M (B 1MB L2-resident).
        const int x = blockIdx.x & 7, j = blockIdx.x >> 3;
        bn0 = (x * 2 + (j & 1)) * 256;
        bm0 = (j >> 1) * 256;
    } else {
        int bid = (blockIdx.x & 7) * (NWG >> 3) + (blockIdx.x >> 3);
        bn0 = (bid % NBX) * 256;
        bm0 = (bid / NBX) * 256;
    }

    const int trow = tid >> 3;                    // 0..63
    const int cg   = (tid & 7) ^ (trow & 7);      // inverse swizzle on source
    const _Float16* Asrc = A + (size_t)(bm0 + trow) * K + cg * 8;
    const _Float16* Bsrc = B + (size_t)(bn0 + trow) * K + cg * 8;

    const int fr  = lane & 15;
    const int fq  = lane >> 4;
    const int s8  = lane & 7;
    const int cb0 = ((fq       ^ s8) << 4);
    const int cb1 = (((4 + fq) ^ s8) << 4);
    const int brb = (wc & 1) * 64;

    const _Float16* Ah[2] = { &lds[0][0][wr][0],      &lds[1][0][wr][0] };
    const _Float16* Bh[2] = { &lds[0][1][wc >> 1][0], &lds[1][1][wc >> 1][0] };

    f32x4 acc[8][4] = {};
    f16x8 aLo[4][2], aHi[4][2], bLo[2][2], bHi[2][2];

#define STAGE_A(buf, h, kk) do { \
    gload_lds16(Asrc + (size_t)((h)*128     ) * K + (kk), (void*)&lds[buf][0][h][       wid*512]); \
    gload_lds16(Asrc + (size_t)((h)*128 + 64) * K + (kk), (void*)&lds[buf][0][h][4096 + wid*512]); } while(0)
#define STAGE_B(buf, h, kk) do { \
    gload_lds16(Bsrc + (size_t)((h)*128     ) * K + (kk), (void*)&lds[buf][1][h][       wid*512]); \
    gload_lds16(Bsrc + (size_t)((h)*128 + 64) * K + (kk), (void*)&lds[buf][1][h][4096 + wid*512]); } while(0)

#define READ_ALO(b) do { _Pragma("unroll") for (int i = 0; i < 4; ++i) { \
    aLo[i][0] = ldf(Ah[b], (i*16+fr)*128 + cb0); \
    aLo[i][1] = ldf(Ah[b], (i*16+fr)*128 + cb1); } } while(0)
#define READ_AHI(b) do { _Pragma("unroll") for (int i = 0; i < 4; ++i) { \
    aHi[i][0] = ldf(Ah[b], ((i+4)*16+fr)*128 + cb0); \
    aHi[i][1] = ldf(Ah[b], ((i+4)*16+fr)*128 + cb1); } } while(0)
#define READ_BLO(b) do { _Pragma("unroll") for (int j = 0; j < 2; ++j) { \
    bLo[j][0] = ldf(Bh[b], (brb + j*16 + fr)*128 + cb0); \
    bLo[j][1] = ldf(Bh[b], (brb + j*16 + fr)*128 + cb1); } } while(0)
#define READ_BHI(b) do { _Pragma("unroll") for (int j = 0; j < 2; ++j) { \
    bHi[j][0] = ldf(Bh[b], (brb + (j+2)*16 + fr)*128 + cb0); \
    bHi[j][1] = ldf(Bh[b], (brb + (j+2)*16 + fr)*128 + cb1); } } while(0)

#define MFMA_BLK(AF, ioff, BF, joff) do { \
    _Pragma("unroll") for (int i = 0; i < 4; ++i) \
    _Pragma("unroll") for (int j = 0; j < 2; ++j) { \
        acc[i+ioff][j+joff] = __builtin_amdgcn_mfma_f32_16x16x32_f16(AF[i][0], BF[j][0], acc[i+ioff][j+joff], 0, 0, 0); \
        acc[i+ioff][j+joff] = __builtin_amdgcn_mfma_f32_16x16x32_f16(AF[i][1], BF[j][1], acc[i+ioff][j+joff], 0, 0, 0); } } while(0)

#define BARRIER() __builtin_amdgcn_s_barrier()
#define VMCNT4()  asm volatile("s_waitcnt vmcnt(4)" ::: "memory")

    // prologue: tile0 -> buf0 (A+B), tile1 B-halves -> buf1
    STAGE_B(0, 0, 0);  STAGE_B(0, 1, 0);
    STAGE_A(0, 0, 0);  STAGE_A(0, 1, 0);
    STAGE_B(1, 0, 64); STAGE_B(1, 1, 64);
    VMCNT4();
    BARRIER();

    float bcol[4], wcol[4];
    #pragma unroll
    for (int j = 0; j < 4; ++j) {
        const int c = bn0 + wc * 64 + j * 16 + fr;
        bcol[j] = bias[c]; wcol[j] = wsum[c];
    }

    for (int it = 0; it < NIT; ++it) {
        const int k1 = it * 128 + 64;
        const int k2 = (it * 128 + 128) & (K - 1);   // wrap staging (R7)
        const int k3 = (it * 128 + 192) & (K - 1);

        // ph0
        READ_ALO(0); READ_BLO(0);
        STAGE_A(1, 0, k1);
        BARRIER();
        __builtin_amdgcn_s_setprio(1); MFMA_BLK(aLo, 0, bLo, 0); __builtin_amdgcn_s_setprio(0);
        BARRIER();
        // ph1
        READ_BHI(0);
        STAGE_A(1, 1, k1);
        BARRIER();
        __builtin_amdgcn_s_setprio(1); MFMA_BLK(aLo, 0, bHi, 2); __builtin_amdgcn_s_setprio(0);
        BARRIER();
        // ph2
        READ_AHI(0);
        STAGE_B(0, 0, k2);
        BARRIER();
        __builtin_amdgcn_s_setprio(1); MFMA_BLK(aHi, 4, bLo, 0); __builtin_amdgcn_s_setprio(0);
        BARRIER();
        // ph3
        STAGE_B(0, 1, k2);
        BARRIER();
        __builtin_amdgcn_s_setprio(1); MFMA_BLK(aHi, 4, bHi, 2); __builtin_amdgcn_s_setprio(0);
        VMCNT4();
        BARRIER();
        // ph4
        READ_ALO(1); READ_BLO(1);
        STAGE_A(0, 0, k2);
        BARRIER();
        __builtin_amdgcn_s_setprio(1); MFMA_BLK(aLo, 0, bLo, 0); __builtin_amdgcn_s_setprio(0);
        BARRIER();
        // ph5
        READ_BHI(1);
        STAGE_A(0, 1, k2);
        BARRIER();
        __builtin_amdgcn_s_setprio(1); MFMA_BLK(aLo, 0, bHi, 2); __builtin_amdgcn_s_setprio(0);
        BARRIER();
        // ph6
        READ_AHI(1);
        STAGE_B(1, 0, k3);
        BARRIER();
        __builtin_amdgcn_s_setprio(1); MFMA_BLK(aHi, 4, bLo, 0); __builtin_amdgcn_s_setprio(0);
        BARRIER();
        // ph7
        STAGE_B(1, 1, k3);
        BARRIER();
        __builtin_amdgcn_s_setprio(1); MFMA_BLK(aHi, 4, bHi, 2); __builtin_amdgcn_s_setprio(0);
        VMCNT4();
        BARRIER();
    }

    // ---- in-block stats: reduce pin -> sst[256] in dead buf0-A (2 KB) ------
    float2* sst = (float2*)&lds[0][0][0][0];
    if constexpr (FIRST) {
        if (tid < 256) sst[tid] = make_float2(0.f, 1.f);
    } else {
        const int row  = tid >> 1;
        const int half = tid & 1;
        const float2* pr = pin + (size_t)(bm0 + row) * NPIN + half * (NPIN / 2);
        float s = 0.f, q = 0.f;
        #pragma unroll
        for (int k = 0; k < NPIN / 2; ++k) { s += pr[k].x; q += pr[k].y; }
        s += __shfl_xor(s, 1); q += __shfl_xor(q, 1);
        if (half == 0) {
            const float mean = s * (1.0f / K);
            const float var  = fmaxf(q * (1.0f / K) - mean * mean, 0.f);
            sst[row] = make_float2(mean, rsqrtf(var + LN_EPS));
        }
    }
    __syncthreads();

    // ---- epilogue through buf1-A (safe per vmcnt ledger) ----
    ushort* eps = (ushort*)&lds[1][0][0][0];   // 64 x 256 ushort = 32 KiB
    #pragma unroll
    for (int pass = 0; pass < 4; ++pass) {
        if (wr == (pass >> 1)) {
            #pragma unroll
            for (int i2 = 0; i2 < 4; ++i2) {
                const int i = (pass & 1) * 4 + i2;
                #pragma unroll
                for (int q = 0; q < 4; ++q) {
                    const int rloc = wr * 128 + i * 16 + fq * 4 + q; // m89
                    const int rl   = rloc - pass * 64;               // 0..63
                    const float2 st = sst[rloc];
                    const float rs = st.y, coef = st.y * st.x;
                    const int key = ((rl >> 2) & 3) << 4;
                    #pragma unroll
                    for (int j = 0; j < 4; ++j) {
                        const float v = rs * acc[i][j][q] - coef * wcol[j] + bcol[j];
                        const int c = wc * 64 + j * 16 + fr;
                        eps[rl * 256 + (c ^ key)] = f2h_bits(v);
                    }
                }
            }
        }
        BARRIER();
        {
            const int rl  = tid >> 3;          // 0..63
            const int a8  = tid & 7;
            const int r   = bm0 + pass * 64 + rl;
            const int key = ((rl >> 2) & 3) << 4;
            float s = 0.f, sq = 0.f;
            ushort* crow = (ushort*)(C + (size_t)r * N + bn0);
            #pragma unroll
            for (int k = 0; k < 4; ++k) {
                const int ch = 8 * k + a8;     // physical 16B chunk
                u32x4 d = *reinterpret_cast<const u32x4*>(&eps[rl * 256 + ch * 8]);
                const f16x8 v = *reinterpret_cast<const f16x8*>(&d);
                #pragma unroll
                for (int e = 0; e < 8; ++e) {
                    const float f = (float)v[e];
                    s += f; sq += f * f;
                }
                *reinterpret_cast<u32x4*>(&crow[(ch * 8) ^ key]) = d;
            }
            s  += __shfl_xor(s, 1);  sq += __shfl_xor(sq, 1);
            s  += __shfl_xor(s, 2);  sq += __shfl_xor(sq, 2);
            s  += __shfl_xor(s, 4);  sq += __shfl_xor(sq, 4);
            if (a8 == 0)
                partials[(size_t)r * NBX + (bn0 >> 8)] = make_float2(s, sq);
        }
        BARRIER();
    }
#undef STAGE_A
#undef STAGE_B
#undef READ_ALO
#undef READ_AHI
#undef READ_BLO
#undef READ_BHI
#undef MFMA_BLK
#undef BARRIER
#undef VMCNT4
}

// ---------------------------------------------------------------------------
// Final: reduce 4 partials/row -> (mean, rstd); out_f32 = (a - mean)*rstd.
// ---------------------------------------------------------------------------
__global__ __launch_bounds__(256)
void ln_final(const _Float16* __restrict__ a, const float2* __restrict__ part,
              float* __restrict__ outp) {
    const int wid  = threadIdx.x >> 6;
    const int lane = threadIdx.x & 63;
    const size_t row = (size_t)blockIdx.x * 4 + wid;

    float s = 0.f, q = 0.f;
    if (lane < 4) { const float2 p = part[row * 4 + lane]; s = p.x; q = p.y; }
    s += __shfl_xor(s, 1); q += __shfl_xor(q, 1);
    s += __shfl_xor(s, 2); q += __shfl_xor(q, 2);
    s = __shfl(s, 0); q = __shfl(q, 0);
    const float mean = s * (1.0f / 1024.f);
    const float var  = fmaxf(q * (1.0f / 1024.f) - mean * mean, 0.f);
    const float rstd = rsqrtf(var + LN_EPS);

    const _Float16* p = a + row * 1024;
    #pragma unroll
    for (int i = 0; i < 2; ++i) {
        f16x8 v = *reinterpret_cast<const f16x8*>(p + i * 512 + lane * 8);
        float* op = outp + row * 1024 + i * 512 + lane * 8;
        float4 o0, o1;
        o0.x = ((float)v[0] - mean) * rstd;
        o0.y = ((float)v[1] - mean) * rstd;
        o0.z = ((float)v[2] - mean) * rstd;
        o0.w = ((float)v[3] - mean) * rstd;
        o1.x = ((float)v[4] - mean) * rstd;
        o1.y = ((float)v[5] - mean) * rstd;
        o1.z = ((float)v[6] - mean) * rstd;
        o1.w = ((float)v[7] - mean) * rstd;
        reinterpret_cast<float4*>(op)[0] = o0;
        reinterpret_cast<float4*>(op)[1] = o1;
    }
}

// ---------------------------------------------------------------------------
extern "C" void kernel_launch(void* const* d_in, const int* in_sizes, int n_in,
                              void* d_out, int out_size, void* d_ws, size_t ws_size,
                              hipStream_t stream) {
    const float* x     = (const float*)d_in[0];
    const float* w_in  = (const float*)d_in[1];
    const float* b_in  = (const float*)d_in[2];
    const float* w_out = (const float*)d_in[3];
    const float* b_out = (const float*)d_in[4];

    constexpr int Mrows = 16384;
    constexpr int Din   = 1024;
    constexpr int Dout  = 4096;

    char* ws = (char*)d_ws;
    _Float16* wib = (_Float16*)ws; ws += (size_t)Dout * Din * 2;      // 8 MB
    _Float16* wob = (_Float16*)ws; ws += (size_t)Din * Dout * 2;      // 8 MB
    _Float16* a2b = (_Float16*)ws; ws += (size_t)Mrows * Din * 2;     // 32 MB
    _Float16* a1b = (_Float16*)ws; ws += (size_t)Mrows * Dout * 2;    // 128 MB
    float* winsum  = (float*)ws;   ws += Dout * 4;                    // 16 KB
    float* woutsum = (float*)ws;   ws += Din * 4;                     // 4 KB
    float2* p1  = (float2*)ws;     ws += (size_t)Mrows * 16 * 8;      // 2 MB
    float2* p2  = (float2*)ws;                                        // 0.5 MB

    const dim3 blk(256);

    conv_f32_f16<<<(Dout * Din / 4) / 256, blk, 0, stream>>>(w_in,  wib, Dout * Din / 4);
    conv_f32_f16<<<(Din * Dout / 4) / 256, blk, 0, stream>>>(w_out, wob, Din * Dout / 4);
    conv_f32_f16<<<(Mrows * Din / 4) / 256, blk, 0, stream>>>(x, a2b, Mrows * Din / 4);
    rowsum_rows<Din> <<<Dout / 4, blk, 0, stream>>>(wib, winsum);
    rowsum_rows<Dout><<<Din / 4,  blk, 0, stream>>>(wob, woutsum);

    for (int it = 0; it < 10; ++it) {
        if (it == 0)
            gemm256_ln<Mrows, Dout, Din, true>
                <<<(Mrows / 256) * (Dout / 256), dim3(512), 0, stream>>>(
                    a2b, wib, b_in, winsum, p2, a1b, p1);
        else
            gemm256_ln<Mrows, Dout, Din, false>
                <<<(Mrows / 256) * (Dout / 256), dim3(512), 0, stream>>>(
                    a2b, wib, b_in, winsum, p2, a1b, p1);
        gemm256_ln<Mrows, Din, Dout, false>
            <<<(Mrows / 256) * (Din / 256), dim3(512), 0, stream>>>(
                a1b, wob, b_out, woutsum, p1, a2b, p2);
    }
    ln_final<<<Mrows / 4, blk, 0, stream>>>(a2b, p2, (float*)d_out);
}

// Round 15
// 2723.640 us; speedup vs baseline: 1.7024x; 1.0127x over previous
//
#include <hip/hip_runtime.h>

// 10x [ y = x @ W_in^T + b_in ; LN ; x = y @ W_out^T + b_out ; LN ]
// Mrows=16384, d_in=1024, d_out=4096. Output f32.
// R15 = R14 (best: 2758us) + two isolated micro-levers:
// (a) last-iteration prefetch guard (drops ~98MB/dispatch wrap-staging
//     waste); last ph3 uses vmcnt(0) -- required, else the ph0/1 buf1-A
//     stages could still be in flight at ph4 (R8b-validated pattern).
// (b) LN stats reduced into registers DURING the prologue (pin loads
//     issued with the stage burst; counted waitcnt drains only them);
//     post-loop writes the 2KB sst table. Removes the post-loop serial
//     cross-XCD L3 latency chain.

typedef __attribute__((ext_vector_type(4))) float    f32x4;
typedef __attribute__((ext_vector_type(8))) _Float16 f16x8;
typedef __attribute__((ext_vector_type(4))) _Float16 f16x4;
typedef __attribute__((ext_vector_type(4))) uint     u32x4;

#define LN_EPS 1e-5f

__device__ __forceinline__ ushort f2h_bits(float f) {
    union { _Float16 h; ushort u; } c; c.h = (_Float16)f; return c.u;
}

typedef const __attribute__((address_space(1))) void* gas_ptr;
typedef __attribute__((address_space(3))) void* las_ptr;

__device__ __forceinline__ void gload_lds16(const void* g, void* l) {
    __builtin_amdgcn_global_load_lds((gas_ptr)g, (las_ptr)l, 16, 0, 0);
}

__device__ __forceinline__ f16x8 ldf(const _Float16* base, int byteoff) {
    return *reinterpret_cast<const f16x8*>(
        reinterpret_cast<const char*>(base) + byteoff);
}

// ---------------------------------------------------------------------------
__global__ __launch_bounds__(256) void conv_f32_f16(
        const float* __restrict__ in, _Float16* __restrict__ outp, int n4) {
    int i = blockIdx.x * 256 + threadIdx.x;
    if (i >= n4) return;
    float4 f = reinterpret_cast<const float4*>(in)[i];
    f16x4 r;
    r[0] = (_Float16)f.x; r[1] = (_Float16)f.y;
    r[2] = (_Float16)f.z; r[3] = (_Float16)f.w;
    *reinterpret_cast<f16x4*>(&outp[(size_t)i * 4]) = r;
}

// ---------------------------------------------------------------------------
template<int W>
__global__ __launch_bounds__(256)
void rowsum_rows(const _Float16* __restrict__ w, float* __restrict__ outp) {
    const int wid  = threadIdx.x >> 6;
    const int lane = threadIdx.x & 63;
    const size_t row = (size_t)blockIdx.x * 4 + wid;
    const _Float16* p = w + row * W;
    float s = 0.f;
    #pragma unroll
    for (int i = 0; i < W / 512; ++i) {
        f16x8 v = *reinterpret_cast<const f16x8*>(p + i * 512 + lane * 8);
        #pragma unroll
        for (int j = 0; j < 8; ++j) s += (float)v[j];
    }
    #pragma unroll
    for (int off = 32; off > 0; off >>= 1) s += __shfl_xor(s, off);
    if (lane == 0) outp[row] = s;
}

// ---------------------------------------------------------------------------
// C[M,N](f16) = LN-fold of A_raw[M,K](f16) * B[N,K]^T(f16):
//   out = rs*(A.B^T) - (rs*mean)*wsum[n] + bias[n]
// (mean,rs) computed from pin (previous kernel's partials, NPIN = K/256
// entries per row) into REGISTERS during the prologue; FIRST: identity.
// Emits partials[row][bn0>>8] = (sum, sumsq) over this block's 256 cols.
// 256x256 tile, BK=64, 512 thr = 8 waves (2Mx4N), 8-phase pipeline.
// ---------------------------------------------------------------------------
template<int M, int N, int K, bool FIRST>
__global__ __launch_bounds__(512)
void gemm256_ln(const _Float16* __restrict__ A, const _Float16* __restrict__ B,
                const float* __restrict__ bias, const float* __restrict__ wsum,
                const float2* __restrict__ pin, _Float16* __restrict__ C,
                float2* __restrict__ partials) {
    constexpr int NT   = K / 64;
    constexpr int NIT  = NT / 2;
    constexpr int NBX  = N / 256;
    constexpr int NWG  = (M / 256) * NBX;
    constexpr int NPIN = K / 256;

    __shared__ __attribute__((aligned(16))) _Float16 lds[2][2][2][8192];

    const int tid  = threadIdx.x;
    const int wid  = tid >> 6;
    const int lane = tid & 63;
    const int wr   = wid >> 2;          // 0..1
    const int wc   = wid & 3;           // 0..3

    int bn0, bm0;
    if constexpr (NBX == 16) {
        // N-strip: XCD x owns N-panels {2x,2x+1}, all M (B 1MB L2-resident).
        const int x = blockIdx.x & 7, j = blockIdx.x >> 3;
        bn0 = (x * 2 + (j & 1)) * 256;
        bm0 = (j >> 1) * 256;
    } else {
        int bid = (blockIdx.x & 7) * (NWG >> 3) + (blockIdx.x >> 3);
        bn0 = (bid % NBX) * 256;
        bm0 = (bid / NBX) * 256;
    }

    const int trow = tid >> 3;                    // 0..63
    const int cg   = (tid & 7) ^ (trow & 7);      // inverse swizzle on source
    const _Float16* Asrc = A + (size_t)(bm0 + trow) * K + cg * 8;
    const _Float16* Bsrc = B + (size_t)(bn0 + trow) * K + cg * 8;

    const int fr  = lane & 15;
    const int fq  = lane >> 4;
    const int s8  = lane & 7;
    const int cb0 = ((fq       ^ s8) << 4);
    const int cb1 = (((4 + fq) ^ s8) << 4);
    const int brb = (wc & 1) * 64;

    const _Float16* Ah[2] = { &lds[0][0][wr][0],      &lds[1][0][wr][0] };
    const _Float16* Bh[2] = { &lds[0][1][wc >> 1][0], &lds[1][1][wc >> 1][0] };

    f32x4 acc[8][4] = {};
    f16x8 aLo[4][2], aHi[4][2], bLo[2][2], bHi[2][2];

#define STAGE_A(buf, h, kk) do { \
    gload_lds16(Asrc + (size_t)((h)*128     ) * K + (kk), (void*)&lds[buf][0][h][       wid*512]); \
    gload_lds16(Asrc + (size_t)((h)*128 + 64) * K + (kk), (void*)&lds[buf][0][h][4096 + wid*512]); } while(0)
#define STAGE_B(buf, h, kk) do { \
    gload_lds16(Bsrc + (size_t)((h)*128     ) * K + (kk), (void*)&lds[buf][1][h][       wid*512]); \
    gload_lds16(Bsrc + (size_t)((h)*128 + 64) * K + (kk), (void*)&lds[buf][1][h][4096 + wid*512]); } while(0)

#define READ_ALO(b) do { _Pragma("unroll") for (int i = 0; i < 4; ++i) { \
    aLo[i][0] = ldf(Ah[b], (i*16+fr)*128 + cb0); \
    aLo[i][1] = ldf(Ah[b], (i*16+fr)*128 + cb1); } } while(0)
#define READ_AHI(b) do { _Pragma("unroll") for (int i = 0; i < 4; ++i) { \
    aHi[i][0] = ldf(Ah[b], ((i+4)*16+fr)*128 + cb0); \
    aHi[i][1] = ldf(Ah[b], ((i+4)*16+fr)*128 + cb1); } } while(0)
#define READ_BLO(b) do { _Pragma("unroll") for (int j = 0; j < 2; ++j) { \
    bLo[j][0] = ldf(Bh[b], (brb + j*16 + fr)*128 + cb0); \
    bLo[j][1] = ldf(Bh[b], (brb + j*16 + fr)*128 + cb1); } } while(0)
#define READ_BHI(b) do { _Pragma("unroll") for (int j = 0; j < 2; ++j) { \
    bHi[j][0] = ldf(Bh[b], (brb + (j+2)*16 + fr)*128 + cb0); \
    bHi[j][1] = ldf(Bh[b], (brb + (j+2)*16 + fr)*128 + cb1); } } while(0)

#define MFMA_BLK(AF, ioff, BF, joff) do { \
    _Pragma("unroll") for (int i = 0; i < 4; ++i) \
    _Pragma("unroll") for (int j = 0; j < 2; ++j) { \
        acc[i+ioff][j+joff] = __builtin_amdgcn_mfma_f32_16x16x32_f16(AF[i][0], BF[j][0], acc[i+ioff][j+joff], 0, 0, 0); \
        acc[i+ioff][j+joff] = __builtin_amdgcn_mfma_f32_16x16x32_f16(AF[i][1], BF[j][1], acc[i+ioff][j+joff], 0, 0, 0); } } while(0)

#define BARRIER() __builtin_amdgcn_s_barrier()
#define VMCNT4()  asm volatile("s_waitcnt vmcnt(4)" ::: "memory")
#define VMCNT0()  asm volatile("s_waitcnt vmcnt(0)" ::: "memory")

    // prologue: tile0 -> buf0 (A+B), tile1 B-halves -> buf1
    STAGE_B(0, 0, 0);  STAGE_B(0, 1, 0);
    STAGE_A(0, 0, 0);  STAGE_A(0, 1, 0);
    STAGE_B(1, 0, 64); STAGE_B(1, 1, 64);

    // LN stats of this block's 256 A-rows -> registers (loads overlap the
    // prologue stage burst; compiler waits only on the older pin loads).
    float st_mean = 0.f, st_rstd = 1.f;
    if constexpr (!FIRST) {
        const int row  = tid >> 1;
        const int half = tid & 1;
        const float2* pr = pin + (size_t)(bm0 + row) * NPIN + half * (NPIN / 2);
        float s = 0.f, q = 0.f;
        #pragma unroll
        for (int k = 0; k < NPIN / 2; ++k) { s += pr[k].x; q += pr[k].y; }
        s += __shfl_xor(s, 1); q += __shfl_xor(q, 1);
        st_mean = s * (1.0f / K);
        const float var = fmaxf(q * (1.0f / K) - st_mean * st_mean, 0.f);
        st_rstd = rsqrtf(var + LN_EPS);
    }

    VMCNT4();
    BARRIER();

    float bcol[4], wcol[4];
    #pragma unroll
    for (int j = 0; j < 4; ++j) {
        const int c = bn0 + wc * 64 + j * 16 + fr;
        bcol[j] = bias[c]; wcol[j] = wsum[c];
    }

    for (int it = 0; it < NIT; ++it) {
        const int k1 = it * 128 + 64;
        const int k2 = (it * 128 + 128) & (K - 1);
        const int k3 = (it * 128 + 192) & (K - 1);
        const bool pf = (it < NIT - 1);   // guard wasted wrap prefetches

        // ph0
        READ_ALO(0); READ_BLO(0);
        STAGE_A(1, 0, k1);
        BARRIER();
        __builtin_amdgcn_s_setprio(1); MFMA_BLK(aLo, 0, bLo, 0); __builtin_amdgcn_s_setprio(0);
        BARRIER();
        // ph1
        READ_BHI(0);
        STAGE_A(1, 1, k1);
        BARRIER();
        __builtin_amdgcn_s_setprio(1); MFMA_BLK(aLo, 0, bHi, 2); __builtin_amdgcn_s_setprio(0);
        BARRIER();
        // ph2
        READ_AHI(0);
        if (pf) STAGE_B(0, 0, k2);
        BARRIER();
        __builtin_amdgcn_s_setprio(1); MFMA_BLK(aHi, 4, bLo, 0); __builtin_amdgcn_s_setprio(0);
        BARRIER();
        // ph3
        if (pf) STAGE_B(0, 1, k2);
        BARRIER();
        __builtin_amdgcn_s_setprio(1); MFMA_BLK(aHi, 4, bHi, 2); __builtin_amdgcn_s_setprio(0);
        if (pf) VMCNT4(); else VMCNT0();  // last iter: buf1-A must fully land
        BARRIER();
        // ph4
        READ_ALO(1); READ_BLO(1);
        if (pf) STAGE_A(0, 0, k2);
        BARRIER();
        __builtin_amdgcn_s_setprio(1); MFMA_BLK(aLo, 0, bLo, 0); __builtin_amdgcn_s_setprio(0);
        BARRIER();
        // ph5
        READ_BHI(1);
        if (pf) STAGE_A(0, 1, k2);
        BARRIER();
        __builtin_amdgcn_s_setprio(1); MFMA_BLK(aLo, 0, bHi, 2); __builtin_amdgcn_s_setprio(0);
        BARRIER();
        // ph6
        READ_AHI(1);
        if (pf) STAGE_B(1, 0, k3);
        BARRIER();
        __builtin_amdgcn_s_setprio(1); MFMA_BLK(aHi, 4, bLo, 0); __builtin_amdgcn_s_setprio(0);
        BARRIER();
        // ph7
        if (pf) STAGE_B(1, 1, k3);
        BARRIER();
        __builtin_amdgcn_s_setprio(1); MFMA_BLK(aHi, 4, bHi, 2); __builtin_amdgcn_s_setprio(0);
        VMCNT4();
        BARRIER();
    }

    // ---- stats table: write precomputed (mean,rstd) into dead buf0-A -------
    float2* sst = (float2*)&lds[0][0][0][0];
    if ((tid & 1) == 0) sst[tid >> 1] = make_float2(st_mean, st_rstd);
    __syncthreads();

    // ---- epilogue through buf1-A (all loads drained: last iter guarded) ----
    ushort* eps = (ushort*)&lds[1][0][0][0];   // 64 x 256 ushort = 32 KiB
    #pragma unroll
    for (int pass = 0; pass < 4; ++pass) {
        if (wr == (pass >> 1)) {
            #pragma unroll
            for (int i2 = 0; i2 < 4; ++i2) {
                const int i = (pass & 1) * 4 + i2;
                #pragma unroll
                for (int q = 0; q < 4; ++q) {
                    const int rloc = wr * 128 + i * 16 + fq * 4 + q; // m89
                    const int rl   = rloc - pass * 64;               // 0..63
                    const float2 st = sst[rloc];
                    const float rs = st.y, coef = st.y * st.x;
                    const int key = ((rl >> 2) & 3) << 4;
                    #pragma unroll
                    for (int j = 0; j < 4; ++j) {
                        const float v = rs * acc[i][j][q] - coef * wcol[j] + bcol[j];
                        const int c = wc * 64 + j * 16 + fr;
                        eps[rl * 256 + (c ^ key)] = f2h_bits(v);
                    }
                }
            }
        }
        BARRIER();
        {
            const int rl  = tid >> 3;          // 0..63
            const int a8  = tid & 7;
            const int r   = bm0 + pass * 64 + rl;
            const int key = ((rl >> 2) & 3) << 4;
            float s = 0.f, sq = 0.f;
            ushort* crow = (ushort*)(C + (size_t)r * N + bn0);
            #pragma unroll
            for (int k = 0; k < 4; ++k) {
                const int ch = 8 * k + a8;     // physical 16B chunk
                u32x4 d = *reinterpret_cast<const u32x4*>(&eps[rl * 256 + ch * 8]);
                const f16x8 v = *reinterpret_cast<const f16x8*>(&d);
                #pragma unroll
                for (int e = 0; e < 8; ++e) {
                    const float f = (float)v[e];
                    s += f; sq += f * f;
                }
                *reinterpret_cast<u32x4*>(&crow[(ch * 8) ^ key]) = d;
            }
            s  += __shfl_xor(s, 1);  sq += __shfl_xor(sq, 1);
            s  += __shfl_xor(s, 2);  sq += __shfl_xor(sq, 2);
            s  += __shfl_xor(s, 4);  sq += __shfl_xor(sq, 4);
            if (a8 == 0)
                partials[(size_t)r * NBX + (bn0 >> 8)] = make_float2(s, sq);
        }
        BARRIER();
    }
#undef STAGE_A
#undef STAGE_B
#undef READ_ALO
#undef READ_AHI
#undef READ_BLO
#undef READ_BHI
#undef MFMA_BLK
#undef BARRIER
#undef VMCNT4
#undef VMCNT0
}

// ---------------------------------------------------------------------------
// Final: reduce 4 partials/row -> (mean, rstd); out_f32 = (a - mean)*rstd.
// ---------------------------------------------------------------------------
__global__ __launch_bounds__(256)
void ln_final(const _Float16* __restrict__ a, const float2* __restrict__ part,
              float* __restrict__ outp) {
    const int wid  = threadIdx.x >> 6;
    const int lane = threadIdx.x & 63;
    const size_t row = (size_t)blockIdx.x * 4 + wid;

    float s = 0.f, q = 0.f;
    if (lane < 4) { const float2 p = part[row * 4 + lane]; s = p.x; q = p.y; }
    s += __shfl_xor(s, 1); q += __shfl_xor(q, 1);
    s += __shfl_xor(s, 2); q += __shfl_xor(q, 2);
    s = __shfl(s, 0); q = __shfl(q, 0);
    const float mean = s * (1.0f / 1024.f);
    const float var  = fmaxf(q * (1.0f / 1024.f) - mean * mean, 0.f);
    const float rstd = rsqrtf(var + LN_EPS);

    const _Float16* p = a + row * 1024;
    #pragma unroll
    for (int i = 0; i < 2; ++i) {
        f16x8 v = *reinterpret_cast<const f16x8*>(p + i * 512 + lane * 8);
        float* op = outp + row * 1024 + i * 512 + lane * 8;
        float4 o0, o1;
        o0.x = ((float)v[0] - mean) * rstd;
        o0.y = ((float)v[1] - mean) * rstd;
        o0.z = ((float)v[2] - mean) * rstd;
        o0.w = ((float)v[3] - mean) * rstd;
        o1.x = ((float)v[4] - mean) * rstd;
        o1.y = ((float)v[5] - mean) * rstd;
        o1.z = ((float)v[6] - mean) * rstd;
        o1.w = ((float)v[7] - mean) * rstd;
        reinterpret_cast<float4*>(op)[0] = o0;
        reinterpret_cast<float4*>(op)[1] = o1;
    }
}

// ---------------------------------------------------------------------------
extern "C" void kernel_launch(void* const* d_in, const int* in_sizes, int n_in,
                              void* d_out, int out_size, void* d_ws, size_t ws_size,
                              hipStream_t stream) {
    const float* x     = (const float*)d_in[0];
    const float* w_in  = (const float*)d_in[1];
    const float* b_in  = (const float*)d_in[2];
    const float* w_out = (const float*)d_in[3];
    const float* b_out = (const float*)d_in[4];

    constexpr int Mrows = 16384;
    constexpr int Din   = 1024;
    constexpr int Dout  = 4096;

    char* ws = (char*)d_ws;
    _Float16* wib = (_Float16*)ws; ws += (size_t)Dout * Din * 2;      // 8 MB
    _Float16* wob = (_Float16*)ws; ws += (size_t)Din * Dout * 2;      // 8 MB
    _Float16* a2b = (_Float16*)ws; ws += (size_t)Mrows * Din * 2;     // 32 MB
    _Float16* a1b = (_Float16*)ws; ws += (size_t)Mrows * Dout * 2;    // 128 MB
    float* winsum  = (float*)ws;   ws += Dout * 4;                    // 16 KB
    float* woutsum = (float*)ws;   ws += Din * 4;                     // 4 KB
    float2* p1  = (float2*)ws;     ws += (size_t)Mrows * 16 * 8;      // 2 MB
    float2* p2  = (float2*)ws;                                        // 0.5 MB

    const dim3 blk(256);

    conv_f32_f16<<<(Dout * Din / 4) / 256, blk, 0, stream>>>(w_in,  wib, Dout * Din / 4);
    conv_f32_f16<<<(Din * Dout / 4) / 256, blk, 0, stream>>>(w_out, wob, Din * Dout / 4);
    conv_f32_f16<<<(Mrows * Din / 4) / 256, blk, 0, stream>>>(x, a2b, Mrows * Din / 4);
    rowsum_rows<Din> <<<Dout / 4, blk, 0, stream>>>(wib, winsum);
    rowsum_rows<Dout><<<Din / 4,  blk, 0, stream>>>(wob, woutsum);

    for (int it = 0; it < 10; ++it) {
        if (it == 0)
            gemm256_ln<Mrows, Dout, Din, true>
                <<<(Mrows / 256) * (Dout / 256), dim3(512), 0, stream>>>(
                    a2b, wib, b_in, winsum, p2, a1b, p1);
        else
            gemm256_ln<Mrows, Dout, Din, false>
                <<<(Mrows / 256) * (Dout / 256), dim3(512), 0, stream>>>(
                    a2b, wib, b_in, winsum, p2, a1b, p1);
        gemm256_ln<Mrows, Din, Dout, false>
            <<<(Mrows / 256) * (Din / 256), dim3(512), 0, stream>>>(
                a1b, wob, b_out, woutsum, p1, a2b, p2);
    }
    ln_final<<<Mrows / 4, blk, 0, stream>>>(a2b, p2, (float*)d_out);
}